// Round 8
// baseline (8001.436 us; speedup 1.0000x reference)
//
#include <hip/hip_runtime.h>
#include <stdint.h>

// RankingLossL1: negative mining (L1 top-K) + margin ranking loss.
// N=50000 rows, D=128, T=1024 anchors/direction, K=10, GAMMA=1.
//
// Round-8 structure. Post-mortem r4/r5/r7: hipcc's PromoteAlloca leaves
// per-thread arrays > ~32 VGPRs in scratch (r7: VGPR_Count=64, 8GB of spill
// WRITES, VALUBusy 28%). Fix: GEMM-style tiling so every private array is
// <=16 registers:
//   * mine_kernel: block = 64 anchors x one N-chunk. Anchors staged once into
//     LDS (padded stride 132 -> 2-way-max conflicts). G rows stream in
//     64-row x 16-dim chunks through a double-buffered padded LDS tile
//     (1 barrier/chunk; global loads issued before compute = async split).
//     Per thread: acc[4][4] over (4 anchors x 4 rows), af[4]/gf[4] fragments.
//   * Per 64-row tile: distances dumped to padded LDS (stride 65), then all
//     256 threads scan (4 sub-scanners per anchor, 16 values each) into
//     register-resident running top-10s. Ties can't change the loss (only
//     distance VALUES enter the sum), so sub-list order is free.
//   * merge_kernel: per (dir,anchor) thread merges 16 chunks x 4 sub-lists.
//   * zero + loss_kernel: one wave per t, shuffle-reduced L1 distances.

#define NROWS 50000
#define DDIM  128
#define TT    1024
#define KK    10
#define NCH   16          // N-chunks: 2 dirs x 16 atiles x 16 chunks = 512 blocks
#define CH    3125        // NROWS/NCH
#define TT2   (2 * TT)
#define BN    64          // G rows per tile
#define TK    16          // dims per chunk (8 chunks over D=128)
#define NTIL  ((CH + BN - 1) / BN)   // 49 row-tiles per chunk
#define AW    132         // sA row stride (words): 4*33, odd s -> 2-way max
#define GW    20          // sG row stride (words): 4*5,  odd s -> 2-way max
#define DW    65          // sD row stride (words): odd  -> conflict-free scan

typedef float f32x4 __attribute__((ext_vector_type(4)));

__device__ __forceinline__ void topk_insert(float (&val)[KK], int (&idx)[KK],
                                            float cv, int ci) {
  // fully unrolled sorted insert (ascending); static indices -> stays in VGPRs
#pragma unroll
  for (int i = 0; i < KK; i++) {
    const bool lt = cv < val[i];
    const float tv = lt ? val[i] : cv;
    const int ti = lt ? idx[i] : ci;
    val[i] = lt ? cv : val[i];
    idx[i] = lt ? ci : idx[i];
    cv = tv;
    ci = ti;
  }
}

// grid: 512 blocks x 256 threads; bid = (dir*16 + atile)*16 + chunk.
// bid%8 == chunk%8 -> each XCD sees only 2 chunks: 3.2MB G working set < L2.
__global__ __launch_bounds__(256, 2) void mine_kernel(
    const float* __restrict__ out1, const float* __restrict__ out2,
    const int* __restrict__ anc1, const int* __restrict__ anc2,
    float* __restrict__ cand_val, int* __restrict__ cand_idx) {
  const int tid = threadIdx.x;
  const int bid = blockIdx.x;
  const int chunk = bid & 15;
  const int combo = bid >> 4;
  const int dir = combo >> 4;
  const int atile = combo & 15;

  const float* __restrict__ A = dir ? out2 : out1;
  const float* __restrict__ G = dir ? out1 : out2;
  const int* __restrict__ anc = dir ? anc2 : anc1;

  const int ag = tid >> 4;  // anchor group: anchors {ag + 16i}
  const int rg = tid & 15;  // row group:    rows    {rts + 16j + rg}

  __shared__ float sA[64 * AW];     // 33.0 KB anchor tile, padded
  __shared__ float sG[2][BN * GW];  // 10.0 KB G dim-chunk, double-buffered
  __shared__ float sD[64 * DW];     // 16.3 KB distance dump, padded

  // ---- stage the 64 gathered anchor rows into padded sA (once) ----
  {
    const int as = tid >> 2, qa = tid & 3;  // 4 threads per anchor row
    const int arow = anc[atile * 64 + as];
    const float* ap = A + (size_t)arow * DDIM + qa * 32;
    float* dp = &sA[as * AW + qa * 32];
#pragma unroll
    for (int c = 0; c < 8; c++)
      *(f32x4*)&dp[4 * c] = *(const f32x4*)&ap[4 * c];
  }

  const int r0 = chunk * CH;
  const int r1 = r0 + CH;
  const int srow = tid >> 2;  // staging: row 0..63
  const int sq = tid & 3;     // staging: 16B quarter of the 64B dim-chunk

  // stage chunk 0 of tile 0 into buffer 0
  {
    f32x4 st = *(const f32x4*)&G[(size_t)(r0 + srow) * DDIM + 4 * sq];
    *(f32x4*)&sG[0][srow * GW + 4 * sq] = st;
  }
  __syncthreads();

  float val[KK];
  int idx[KK];
#pragma unroll
  for (int i = 0; i < KK; i++) {
    val[i] = 3.4e38f;
    idx[i] = 0;
  }

  for (int t = 0; t < NTIL; t++) {
    const int ts = r0 + t * BN;                       // unclamped tile start
    const int rts = (ts + BN <= r1) ? ts : (r1 - BN); // clamped (tail overlap)
    const int nts = ts + BN;                          // next tile start
    const int nrts = (nts + BN <= r1) ? nts : (r1 - BN);

    float acc[4][4];
#pragma unroll
    for (int i = 0; i < 4; i++)
#pragma unroll
      for (int j = 0; j < 4; j++) acc[i][j] = 0.f;

#pragma unroll 2
    for (int dc = 0; dc < 8; dc++) {
      const int b = dc & 1;
      // issue next chunk's global load BEFORE compute (latency hides under it)
      f32x4 st;
      const bool more = (dc < 7) || (t + 1 < NTIL);
      if (more) {
        const int lrow = (dc < 7) ? (rts + srow) : (nrts + srow);
        const int ldim = (dc < 7) ? ((dc + 1) * TK) : 0;
        st = *(const f32x4*)&G[(size_t)lrow * DDIM + ldim + 4 * sq];
      }
      // compute: 4 sub-steps of 4 dims
#pragma unroll
      for (int dd = 0; dd < TK; dd += 4) {
        f32x4 af[4], gf[4];
#pragma unroll
        for (int i = 0; i < 4; i++)
          af[i] = *(const f32x4*)&sA[(ag + 16 * i) * AW + dc * TK + dd];
#pragma unroll
        for (int j = 0; j < 4; j++)
          gf[j] = *(const f32x4*)&sG[b][(16 * j + rg) * GW + dd];
#pragma unroll
        for (int i = 0; i < 4; i++)
#pragma unroll
          for (int j = 0; j < 4; j++) {
            const f32x4 d = af[i] - gf[j];
            acc[i][j] += (fabsf(d.x) + fabsf(d.y)) + (fabsf(d.z) + fabsf(d.w));
          }
      }
      // write staged data into the other buffer, then one barrier
      if (more) *(f32x4*)&sG[b ^ 1][srow * GW + 4 * sq] = st;
      __syncthreads();
    }

    // dump the 64x64 distance tile to padded LDS
#pragma unroll
    for (int i = 0; i < 4; i++)
#pragma unroll
      for (int j = 0; j < 4; j++)
        sD[(ag + 16 * i) * DW + 16 * j + rg] = acc[i][j];
    __syncthreads();

    // scan: thread handles anchor (tid&63), quarter (tid>>6) -> 16 values
    {
      const int a = tid & 63;
      const int q = tid >> 6;
      const float* dp = &sD[a * DW + 16 * q];
#pragma unroll
      for (int r = 0; r < 16; r++) {
        const float v = dp[r];
        const int row = rts + 16 * q + r;
        if (v < val[KK - 1] && row >= ts) topk_insert(val, idx, v, row);
      }
    }
    // no barrier needed: next touch of sD is after next tile's chunk barriers
  }

  // write this (chunk, quarter) sub-list; layout [(chunk*4+q)*K + i][slot]
  {
    const int a = tid & 63;
    const int q = tid >> 6;
    const int slot = dir * TT + atile * 64 + a;
#pragma unroll
    for (int i = 0; i < KK; i++) {
      const size_t o = (size_t)((chunk * 4 + q) * KK + i) * TT2 + slot;
      cand_val[o] = val[i];
      cand_idx[o] = idx[i];
    }
  }
}

__global__ void merge_kernel(const float* __restrict__ cand_val,
                             const int* __restrict__ cand_idx,
                             int* __restrict__ neg) {
  const int slot = blockIdx.x * blockDim.x + threadIdx.x;  // dir*TT + anchor
  if (slot >= TT2) return;
  float val[KK];
  int idx[KK];
#pragma unroll
  for (int i = 0; i < KK; i++) {
    val[i] = 3.4e38f;
    idx[i] = 0;
  }
  for (int c = 0; c < NCH * 4 * KK; c++) {  // 640 candidates, coalesced
    const size_t o = (size_t)c * TT2 + slot;
    const float v = cand_val[o];
    if (v < val[KK - 1]) topk_insert(val, idx, v, cand_idx[o]);
  }
#pragma unroll
  for (int i = 0; i < KK; i++) neg[(size_t)slot * KK + i] = idx[i];
}

__global__ void zero_kernel(float* __restrict__ out) {
  if (threadIdx.x == 0) out[0] = 0.f;
}

typedef float f32x2 __attribute__((ext_vector_type(2)));

__global__ void loss_kernel(const float* __restrict__ out1,
                            const float* __restrict__ out2,
                            const int* __restrict__ anc1,
                            const int* __restrict__ anc2,
                            const int* __restrict__ neg,  // [2][TT][KK]
                            float* __restrict__ out) {
  const int lane = threadIdx.x & 63;
  const int w = threadIdx.x >> 6;
  const int t = blockIdx.x * 4 + w;  // one wave per t
  const int a1 = anc1[t];
  const int a2 = anc2[t];
  const int e = lane * 2;  // 2 elements per lane

  const f32x2 x1 = *(const f32x2*)(out1 + (size_t)a1 * DDIM + e);
  const f32x2 x2 = *(const f32x2*)(out2 + (size_t)a2 * DDIM + e);

  float ap = fabsf(x1.x - x2.x) + fabsf(x1.y - x2.y);
#pragma unroll
  for (int o = 32; o > 0; o >>= 1) ap += __shfl_xor(ap, o, 64);
  const float Dm = ap + 1.0f;  // GAMMA = 1

  float s = 0.f;
  for (int k = 0; k < KK; k++) {
    const int n1 = neg[(size_t)t * KK + k];         // row of out2
    const int n2 = neg[(size_t)(TT + t) * KK + k];  // row of out1
    const f32x2 v1 = *(const f32x2*)(out2 + (size_t)n1 * DDIM + e);
    const f32x2 v2 = *(const f32x2*)(out1 + (size_t)n2 * DDIM + e);
    float d1 = fabsf(x1.x - v1.x) + fabsf(x1.y - v1.y);
    float d2 = fabsf(x2.x - v2.x) + fabsf(x2.y - v2.y);
#pragma unroll
    for (int o = 32; o > 0; o >>= 1) {
      d1 += __shfl_xor(d1, o, 64);
      d2 += __shfl_xor(d2, o, 64);
    }
    s += fmaxf(Dm - d1, 0.f) + fmaxf(Dm - d2, 0.f);
  }
  if (lane == 0) atomicAdd(out, s * (1.0f / (TT * KK)));
}

extern "C" void kernel_launch(void* const* d_in, const int* in_sizes, int n_in,
                              void* d_out, int out_size, void* d_ws,
                              size_t ws_size, hipStream_t stream) {
  const float* out1 = (const float*)d_in[0];
  const float* out2 = (const float*)d_in[1];
  const int* anc1 = (const int*)d_in[2];
  const int* anc2 = (const int*)d_in[3];

  // workspace: cand_val (5.24MB) | cand_idx (5.24MB) | neg (80KB)
  float* cand_val = (float*)d_ws;
  int* cand_idx = (int*)(cand_val + (size_t)NCH * 4 * KK * TT2);
  int* neg = cand_idx + (size_t)NCH * 4 * KK * TT2;
  float* out = (float*)d_out;

  hipLaunchKernelGGL(mine_kernel, dim3(2 * 16 * NCH), dim3(256), 0, stream,
                     out1, out2, anc1, anc2, cand_val, cand_idx);
  hipLaunchKernelGGL(merge_kernel, dim3(8), dim3(256), 0, stream, cand_val,
                     cand_idx, neg);
  hipLaunchKernelGGL(zero_kernel, dim3(1), dim3(64), 0, stream, out);
  hipLaunchKernelGGL(loss_kernel, dim3(TT / 4), dim3(256), 0, stream, out1,
                     out2, anc1, anc2, neg, out);
}